// Round 1
// baseline (1516.779 us; speedup 1.0000x reference)
//
#include <hip/hip_runtime.h>
#include <math.h>

// PhysicsResidual: wave-equation residual of a 6x tanh MLP (width 128, in=4)
// via 2nd-order forward-mode AD along the 4 coordinate directions.
// State per point: 9 vectors of 128 floats (h, 4x d/dx_k, 4x d2/dx_k2).

constexpr int TPB  = 256;  // threads per block
constexpr int BPTS = 16;   // points per block
constexpr int NPT  = 8;    // neurons per thread (128 / 16 groups)
constexpr int H    = 128;
constexpr int WPAD = 132;  // padded row stride (floats)

__device__ __forceinline__ float fast_tanh(float v) {
    // tanh(v) = sign(v) * (1 - e) / (1 + e), e = exp(-2|v|)
    float e = __expf(-2.0f * fabsf(v));
    float r = __builtin_amdgcn_rcpf(1.0f + e);
    float t = (1.0f - e) * r;
    return copysignf(t, v);
}

__global__ __launch_bounds__(TPB) void pinn_wave_residual(
    const float* __restrict__ t, const float* __restrict__ x,
    const float* __restrict__ y, const float* __restrict__ z,
    const float* __restrict__ W0, const float* __restrict__ b0,
    const float* __restrict__ W1, const float* __restrict__ b1,
    const float* __restrict__ W2, const float* __restrict__ b2,
    const float* __restrict__ W3, const float* __restrict__ b3,
    const float* __restrict__ W4, const float* __restrict__ b4,
    const float* __restrict__ W5, const float* __restrict__ b5,
    const float* __restrict__ W6, float* __restrict__ out, int N)
{
    // LDS: weight tile (128x132 = 67.6 KB) + state (9*16*132 = 74.3 KB) + reduce
    __shared__ float sW[H * WPAD];            // 67584 B
    __shared__ float sX[9 * BPTS * WPAD];     // 76032 B
    __shared__ float sRed[BPTS * 17];         // 1088 B  -> total ~141.3 KiB

    const int tid = threadIdx.x;
    const int p   = tid & 15;        // local point
    const int g   = tid >> 4;        // neuron group; owns i = g + 16*ii
    int gpt = blockIdx.x * BPTS + p;
    const bool valid = (gpt < N);
    if (gpt >= N) gpt = N - 1;       // clamp (value unused)

    const float pt0 = t[gpt], pt1 = x[gpt], pt2 = y[gpt], pt3 = z[gpt];

    // ---------------- layer 0 (input dim 4, analytic tangents) -------------
    // z = W0 p + b0 ; zdot_k = W0[:,k] ; zddot_k = 0
    #pragma unroll
    for (int ii = 0; ii < NPT; ++ii) {
        const int i = g + 16 * ii;
        const float4 w = *(const float4*)&W0[i * 4];
        const float zv = fmaf(w.x, pt0, fmaf(w.y, pt1, fmaf(w.z, pt2, fmaf(w.w, pt3, b0[i]))));
        const float hv = fast_tanh(zv);
        const float s  = 1.0f - hv * hv;
        sX[(0 * BPTS + p) * WPAD + i] = hv;
        const float wk[4] = { w.x, w.y, w.z, w.w };
        #pragma unroll
        for (int k = 0; k < 4; ++k) {
            const float zd = wk[k];
            sX[((1 + k) * BPTS + p) * WPAD + i] = s * zd;
            sX[((5 + k) * BPTS + p) * WPAD + i] = -2.0f * hv * s * zd * zd;
        }
    }

    const float* Wl[5] = { W1, W2, W3, W4, W5 };
    const float* bl[5] = { b1, b2, b3, b4, b5 };

    // ---------------- layers 1..5 (128x128) --------------------------------
    for (int l = 0; l < 5; ++l) {
        __syncthreads();
        // stage W into LDS (row-major, padded rows)
        {
            const float4* src = (const float4*)Wl[l];
            #pragma unroll
            for (int c = 0; c < 16; ++c) {
                const int f   = tid + c * TPB;   // float4 index 0..4095
                const int row = f >> 5;          // 32 float4 per row
                const int c4  = f & 31;
                *(float4*)&sW[row * WPAD + c4 * 4] = src[f];
            }
        }
        __syncthreads();

        // 9 matvecs: acc[v][ii] = sum_j W[i][j] * X[v][p][j]
        float acc[9][NPT];
        #pragma unroll
        for (int v = 0; v < 9; ++v)
            #pragma unroll
            for (int ii = 0; ii < NPT; ++ii) acc[v][ii] = 0.0f;

        const int xbase = p * WPAD;
        #pragma unroll 2
        for (int j4 = 0; j4 < 32; ++j4) {
            float4 xv[9];
            #pragma unroll
            for (int v = 0; v < 9; ++v)
                xv[v] = *(const float4*)&sX[(v * BPTS) * WPAD + xbase + j4 * 4];
            #pragma unroll
            for (int ii = 0; ii < NPT; ++ii) {
                const float4 w = *(const float4*)&sW[(g + 16 * ii) * WPAD + j4 * 4];
                #pragma unroll
                for (int v = 0; v < 9; ++v) {
                    acc[v][ii] = fmaf(w.x, xv[v].x,
                                 fmaf(w.y, xv[v].y,
                                 fmaf(w.z, xv[v].z,
                                 fmaf(w.w, xv[v].w, acc[v][ii]))));
                }
            }
        }

        if (l < 4) {
            __syncthreads();   // all X reads done before overwrite
            #pragma unroll
            for (int ii = 0; ii < NPT; ++ii) {
                const int i = g + 16 * ii;
                const float zv = acc[0][ii] + bl[l][i];
                const float hv = fast_tanh(zv);
                const float s  = 1.0f - hv * hv;
                sX[(0 * BPTS + p) * WPAD + i] = hv;
                #pragma unroll
                for (int k = 0; k < 4; ++k) {
                    const float zd  = acc[1 + k][ii];
                    const float zdd = acc[5 + k][ii];
                    sX[((1 + k) * BPTS + p) * WPAD + i] = s * zd;
                    sX[((5 + k) * BPTS + p) * WPAD + i] =
                        fmaf(s, zdd, -2.0f * hv * s * zd * zd);
                }
            }
        } else {
            // last tanh layer + linear head fused: res = W6 . (dd0 - dd1 - dd2 - dd3)
            float part = 0.0f;
            #pragma unroll
            for (int ii = 0; ii < NPT; ++ii) {
                const int i = g + 16 * ii;
                const float zv = acc[0][ii] + bl[4][i];
                const float hv = fast_tanh(zv);
                const float s  = 1.0f - hv * hv;
                float sum_dd = 0.0f;
                #pragma unroll
                for (int k = 0; k < 4; ++k) {
                    const float zd  = acc[1 + k][ii];
                    const float zdd = acc[5 + k][ii];
                    const float ndd = fmaf(s, zdd, -2.0f * hv * s * zd * zd);
                    sum_dd += (k == 0) ? ndd : -ndd;
                }
                part += W6[i] * sum_dd;
            }
            sRed[p * 17 + g] = part;
        }
    }

    __syncthreads();
    if (tid < BPTS) {
        float r = 0.0f;
        #pragma unroll
        for (int g2 = 0; g2 < 16; ++g2) r += sRed[tid * 17 + g2];
        const int o = blockIdx.x * BPTS + tid;
        if (o < N) out[o] = r;
    }
}

extern "C" void kernel_launch(void* const* d_in, const int* in_sizes, int n_in,
                              void* d_out, int out_size, void* d_ws, size_t ws_size,
                              hipStream_t stream) {
    const float* t  = (const float*)d_in[0];
    const float* x  = (const float*)d_in[1];
    const float* y  = (const float*)d_in[2];
    const float* z  = (const float*)d_in[3];
    const float* W0 = (const float*)d_in[4];
    const float* b0 = (const float*)d_in[5];
    const float* W1 = (const float*)d_in[6];
    const float* b1 = (const float*)d_in[7];
    const float* W2 = (const float*)d_in[8];
    const float* b2 = (const float*)d_in[9];
    const float* W3 = (const float*)d_in[10];
    const float* b3 = (const float*)d_in[11];
    const float* W4 = (const float*)d_in[12];
    const float* b4 = (const float*)d_in[13];
    const float* W5 = (const float*)d_in[14];
    const float* b5 = (const float*)d_in[15];
    const float* W6 = (const float*)d_in[16];
    // d_in[17] = b6: unused (drops out of the second derivative)

    const int N = in_sizes[0];
    float* out = (float*)d_out;

    const int grid = (N + BPTS - 1) / BPTS;
    pinn_wave_residual<<<grid, TPB, 0, stream>>>(
        t, x, y, z, W0, b0, W1, b1, W2, b2, W3, b3, W4, b4, W5, b5, W6, out, N);
}

// Round 2
// 895.188 us; speedup vs baseline: 1.6944x; 1.6944x over previous
//
#include <hip/hip_runtime.h>
#include <math.h>

// PhysicsResidual: wave-equation residual of a 6x tanh MLP (width 128, in=4)
// via 2nd-order forward-mode AD. KEY ALGEBRA: the 4 second-derivative tangents
// propagate linearly (same per-layer coefficient s), so we carry only the
// signed combination q = u_tt'' - u_xx'' - u_yy'' - u_zz'' as ONE vector:
//   linear:  q_z = W q_x
//   tanh:    q_a = s*q_z - 2*a*s*(zd_t^2 - zd_x^2 - zd_y^2 - zd_z^2)
// State per point: 6 vectors of 128 floats (h, 4x d/dx_k, q).
// W is NOT staged in LDS (16-lane-broadcast reads from L1/L2) so LDS = 51.8KB
// -> 3 blocks/CU = 12 waves/CU instead of 4.

constexpr int TPB  = 256;  // threads per block
constexpr int BPTS = 16;   // points per block
constexpr int NPT  = 8;    // neurons per thread (128 / 16 groups)
constexpr int H    = 128;
constexpr int WPAD = 132;  // padded row stride (floats), keeps 16B alignment
constexpr int NV   = 6;    // 0=value, 1..4=first derivs, 5=q (signed 2nd-deriv combo)

__device__ __forceinline__ float fast_tanh(float v) {
    float e = __expf(-2.0f * fabsf(v));
    float r = __builtin_amdgcn_rcpf(1.0f + e);
    float t = (1.0f - e) * r;
    return copysignf(t, v);
}

__global__ __launch_bounds__(TPB, 3) void pinn_wave_residual(
    const float* __restrict__ t, const float* __restrict__ x,
    const float* __restrict__ y, const float* __restrict__ z,
    const float* __restrict__ W0, const float* __restrict__ b0,
    const float* __restrict__ W1, const float* __restrict__ b1,
    const float* __restrict__ W2, const float* __restrict__ b2,
    const float* __restrict__ W3, const float* __restrict__ b3,
    const float* __restrict__ W4, const float* __restrict__ b4,
    const float* __restrict__ W5, const float* __restrict__ b5,
    const float* __restrict__ W6, float* __restrict__ out, int N)
{
    __shared__ float sX[NV * BPTS * WPAD];    // 50688 B
    __shared__ float sRed[BPTS * 17];         // 1088 B -> 51776 B total

    const int tid = threadIdx.x;
    const int p   = tid & 15;        // local point
    const int g   = tid >> 4;        // neuron group; owns i = g + 16*ii
    int gpt = blockIdx.x * BPTS + p;
    if (gpt >= N) gpt = N - 1;       // clamp (value unused for OOB)

    const float pt0 = t[gpt], pt1 = x[gpt], pt2 = y[gpt], pt3 = z[gpt];

    // ---------------- layer 0 (input dim 4, analytic tangents) -------------
    #pragma unroll
    for (int ii = 0; ii < NPT; ++ii) {
        const int i = g + 16 * ii;
        const float4 w = *(const float4*)&W0[i * 4];
        const float zv = fmaf(w.x, pt0, fmaf(w.y, pt1, fmaf(w.z, pt2, fmaf(w.w, pt3, b0[i]))));
        const float hv = fast_tanh(zv);
        const float s  = 1.0f - hv * hv;
        sX[(0 * BPTS + p) * WPAD + i] = hv;
        sX[(1 * BPTS + p) * WPAD + i] = s * w.x;
        sX[(2 * BPTS + p) * WPAD + i] = s * w.y;
        sX[(3 * BPTS + p) * WPAD + i] = s * w.z;
        sX[(4 * BPTS + p) * WPAD + i] = s * w.w;
        // q after layer0: s*0 - 2*h*s*(wx^2 - wy^2 - wz^2 - ww^2)
        const float ssq = ((w.x * w.x - w.y * w.y) - w.z * w.z) - w.w * w.w;
        sX[(5 * BPTS + p) * WPAD + i] = -2.0f * hv * s * ssq;
    }

    const float* Wl[5] = { W1, W2, W3, W4, W5 };
    const float* bl[5] = { b1, b2, b3, b4, b5 };

    // ---------------- layers 1..5 (128x128) --------------------------------
    for (int l = 0; l < 5; ++l) {
        __syncthreads();   // X fully written

        float acc[NV][NPT];
        #pragma unroll
        for (int v = 0; v < NV; ++v)
            #pragma unroll
            for (int ii = 0; ii < NPT; ++ii) acc[v][ii] = 0.0f;

        // hoisted W row pointers (4 distinct rows per wave instr -> L1 broadcast)
        const float* __restrict__ Wcur = Wl[l];
        const float* wrow[NPT];
        #pragma unroll
        for (int ii = 0; ii < NPT; ++ii) wrow[ii] = Wcur + (g + 16 * ii) * H;

        const float* __restrict__ xbase = &sX[p * WPAD];

        #pragma unroll 4
        for (int j4 = 0; j4 < 32; ++j4) {
            float4 xv[NV];
            #pragma unroll
            for (int v = 0; v < NV; ++v)
                xv[v] = *(const float4*)&xbase[v * (BPTS * WPAD) + j4 * 4];
            #pragma unroll
            for (int ii = 0; ii < NPT; ++ii) {
                const float4 w = *(const float4*)&wrow[ii][j4 * 4];
                #pragma unroll
                for (int v = 0; v < NV; ++v) {
                    acc[v][ii] = fmaf(w.x, xv[v].x,
                                 fmaf(w.y, xv[v].y,
                                 fmaf(w.z, xv[v].z,
                                 fmaf(w.w, xv[v].w, acc[v][ii]))));
                }
            }
        }

        if (l < 4) {
            __syncthreads();   // all X reads done before overwrite
            const float* __restrict__ bcur = bl[l];
            #pragma unroll
            for (int ii = 0; ii < NPT; ++ii) {
                const int i = g + 16 * ii;
                const float zv = acc[0][ii] + bcur[i];
                const float hv = fast_tanh(zv);
                const float s  = 1.0f - hv * hv;
                const float d0 = acc[1][ii], d1 = acc[2][ii];
                const float d2 = acc[3][ii], d3 = acc[4][ii];
                sX[(0 * BPTS + p) * WPAD + i] = hv;
                sX[(1 * BPTS + p) * WPAD + i] = s * d0;
                sX[(2 * BPTS + p) * WPAD + i] = s * d1;
                sX[(3 * BPTS + p) * WPAD + i] = s * d2;
                sX[(4 * BPTS + p) * WPAD + i] = s * d3;
                const float ssq = ((d0 * d0 - d1 * d1) - d2 * d2) - d3 * d3;
                sX[(5 * BPTS + p) * WPAD + i] = fmaf(s, acc[5][ii], -2.0f * hv * s * ssq);
            }
        } else {
            // last tanh layer + linear head fused: res = W6 . q_final
            float part = 0.0f;
            const float* __restrict__ bcur = bl[4];
            #pragma unroll
            for (int ii = 0; ii < NPT; ++ii) {
                const int i = g + 16 * ii;
                const float zv = acc[0][ii] + bcur[i];
                const float hv = fast_tanh(zv);
                const float s  = 1.0f - hv * hv;
                const float d0 = acc[1][ii], d1 = acc[2][ii];
                const float d2 = acc[3][ii], d3 = acc[4][ii];
                const float ssq = ((d0 * d0 - d1 * d1) - d2 * d2) - d3 * d3;
                const float qf  = fmaf(s, acc[5][ii], -2.0f * hv * s * ssq);
                part += W6[i] * qf;
            }
            sRed[p * 17 + g] = part;
        }
    }

    __syncthreads();
    if (tid < BPTS) {
        float r = 0.0f;
        #pragma unroll
        for (int g2 = 0; g2 < 16; ++g2) r += sRed[tid * 17 + g2];
        const int o = blockIdx.x * BPTS + tid;
        if (o < N) out[o] = r;
    }
}

extern "C" void kernel_launch(void* const* d_in, const int* in_sizes, int n_in,
                              void* d_out, int out_size, void* d_ws, size_t ws_size,
                              hipStream_t stream) {
    const float* t  = (const float*)d_in[0];
    const float* x  = (const float*)d_in[1];
    const float* y  = (const float*)d_in[2];
    const float* z  = (const float*)d_in[3];
    const float* W0 = (const float*)d_in[4];
    const float* b0 = (const float*)d_in[5];
    const float* W1 = (const float*)d_in[6];
    const float* b1 = (const float*)d_in[7];
    const float* W2 = (const float*)d_in[8];
    const float* b2 = (const float*)d_in[9];
    const float* W3 = (const float*)d_in[10];
    const float* b3 = (const float*)d_in[11];
    const float* W4 = (const float*)d_in[12];
    const float* b4 = (const float*)d_in[13];
    const float* W5 = (const float*)d_in[14];
    const float* b5 = (const float*)d_in[15];
    const float* W6 = (const float*)d_in[16];
    // d_in[17] = b6: unused (drops out of all derivatives)

    const int N = in_sizes[0];
    float* out = (float*)d_out;

    const int grid = (N + BPTS - 1) / BPTS;
    pinn_wave_residual<<<grid, TPB, 0, stream>>>(
        t, x, y, z, W0, b0, W1, b1, W2, b2, W3, b3, W4, b4, W5, b5, W6, out, N);
}

// Round 3
// 264.538 us; speedup vs baseline: 5.7337x; 3.3840x over previous
//
#include <hip/hip_runtime.h>
#include <hip/hip_fp16.h>
#include <math.h>

// PhysicsResidual via 2nd-order forward-mode AD, split-fp16 MFMA edition.
// State per point: 6 vectors of 128 (h, 4 first derivs, q = signed 2nd-deriv combo).
// Per block: 32 points -> GEMM M=192 (6v x 32p), K=128, N=128 per layer.
// Each fp32 operand carried as fp16 hi+lo; A*B ~= Ah*Bh + Ah*Bl + Al*Bh (fp32 acc).
// C/D layout (verified m89): col = lane&15, row = (lane>>4)*4 + reg.
// A layout (canonical): row = lane&15, k = (lane>>4)*8 + e.
// B layout (canonical): col = lane&15, k = (lane>>4)*8 + e  (B[k][n] = W[n][k]).

typedef _Float16 f16x8 __attribute__((ext_vector_type(8)));
typedef float    f32x4 __attribute__((ext_vector_type(4)));

constexpr int TPB  = 512;
constexpr int P    = 32;    // points per block
constexpr int H    = 128;
constexpr int XPAD = 136;   // fp16 per padded X row (272 B: 16B-aligned, bank-spread)
constexpr int MR   = 6 * P; // 192 state rows

__device__ __forceinline__ float fast_tanh(float v) {
    float e = __expf(-2.0f * fabsf(v));
    float r = __builtin_amdgcn_rcpf(1.0f + e);
    return copysignf((1.0f - e) * r, v);
}

__device__ __forceinline__ void split_f16(float v, _Float16& hi, _Float16& lo) {
    hi = (_Float16)v;
    lo = (_Float16)(v - (float)hi);
}

__global__ __launch_bounds__(TPB, 2) void pinn_mfma(
    const float* __restrict__ t, const float* __restrict__ x,
    const float* __restrict__ y, const float* __restrict__ z,
    const float* __restrict__ W0, const float* __restrict__ b0,
    const float* __restrict__ W1, const float* __restrict__ b1,
    const float* __restrict__ W2, const float* __restrict__ b2,
    const float* __restrict__ W3, const float* __restrict__ b3,
    const float* __restrict__ W4, const float* __restrict__ b4,
    const float* __restrict__ W5, const float* __restrict__ b5,
    const float* __restrict__ W6, float* __restrict__ out, int N)
{
    __shared__ _Float16 sXhi[MR * XPAD];   // 52224 B
    __shared__ _Float16 sXlo[MR * XPAD];   // 52224 B
    __shared__ float    sRed[4][P];        // 512 B   -> ~102.5 KiB total

    const int tid  = threadIdx.x;
    const int lane = tid & 63;
    const int w    = tid >> 6;     // wave 0..7
    const int wm   = w >> 2;       // 0..1 : point half (rows)
    const int wn   = w & 3;        // 0..3 : 32-col output strip
    const int l15  = lane & 15;
    const int l4   = lane >> 4;    // 0..3
    const int gb   = blockIdx.x * P;

    // ---------------- layer 0 (input dim 4, analytic tangents) -------------
    {
        const int p0 = tid >> 4;           // 0..31
        const int i0 = tid & 15;
        int gp = gb + p0; if (gp >= N) gp = N - 1;
        const float pt0 = t[gp], pt1 = x[gp], pt2 = y[gp], pt3 = z[gp];
        #pragma unroll
        for (int j = 0; j < 8; ++j) {
            const int i = i0 + 16 * j;
            const float4 wv = *(const float4*)&W0[i * 4];
            const float zv = fmaf(wv.x, pt0, fmaf(wv.y, pt1, fmaf(wv.z, pt2, fmaf(wv.w, pt3, b0[i]))));
            const float hv = fast_tanh(zv);
            const float s  = 1.0f - hv * hv;
            const float ssq = ((wv.x * wv.x - wv.y * wv.y) - wv.z * wv.z) - wv.w * wv.w;
            const float nv[6] = { hv, s * wv.x, s * wv.y, s * wv.z, s * wv.w,
                                  -2.0f * hv * s * ssq };
            #pragma unroll
            for (int v = 0; v < 6; ++v) {
                const int idx = (v * P + p0) * XPAD + i;
                _Float16 h_, o_; split_f16(nv[v], h_, o_);
                sXhi[idx] = h_; sXlo[idx] = o_;
            }
        }
    }
    __syncthreads();

    const float* Wl[5] = { W1, W2, W3, W4, W5 };
    const float* bl[5] = { b1, b2, b3, b4, b5 };

    for (int l = 0; l < 5; ++l) {
        // ---- B-fragments (W hi/lo) straight from global into registers ----
        // B[k][n] = W[n][k]: lane reads row n = wn*32+nt*16+l15, k = ks*32+l4*8 .. +7
        f16x8 bh[2][4], bo[2][4];
        const float* __restrict__ Wc = Wl[l];
        #pragma unroll
        for (int nt = 0; nt < 2; ++nt) {
            const int n = wn * 32 + nt * 16 + l15;
            #pragma unroll
            for (int ks = 0; ks < 4; ++ks) {
                const int k0 = ks * 32 + l4 * 8;
                const float4 u0 = *(const float4*)&Wc[n * H + k0];
                const float4 u1 = *(const float4*)&Wc[n * H + k0 + 4];
                const float vv[8] = { u0.x, u0.y, u0.z, u0.w, u1.x, u1.y, u1.z, u1.w };
                #pragma unroll
                for (int e = 0; e < 8; ++e) {
                    _Float16 h_, o_; split_f16(vv[e], h_, o_);
                    bh[nt][ks][e] = h_; bo[nt][ks][e] = o_;
                }
            }
        }

        // ---- GEMM: acc[v][nt] over K=128 in 4 steps, 3-product split ----
        f32x4 acc[6][2];
        #pragma unroll
        for (int v = 0; v < 6; ++v)
            #pragma unroll
            for (int nt = 0; nt < 2; ++nt) acc[v][nt] = (f32x4){0.f, 0.f, 0.f, 0.f};

        #pragma unroll
        for (int ks = 0; ks < 4; ++ks) {
            const int k0 = ks * 32 + l4 * 8;
            f16x8 ah[6], ao[6];
            #pragma unroll
            for (int v = 0; v < 6; ++v) {
                const int row = v * P + wm * 16 + l15;
                ah[v] = *(const f16x8*)&sXhi[row * XPAD + k0];
                ao[v] = *(const f16x8*)&sXlo[row * XPAD + k0];
            }
            #pragma unroll
            for (int v = 0; v < 6; ++v)
                #pragma unroll
                for (int nt = 0; nt < 2; ++nt) {
                    acc[v][nt] = __builtin_amdgcn_mfma_f32_16x16x32_f16(ah[v], bh[nt][ks], acc[v][nt], 0, 0, 0);
                    acc[v][nt] = __builtin_amdgcn_mfma_f32_16x16x32_f16(ah[v], bo[nt][ks], acc[v][nt], 0, 0, 0);
                    acc[v][nt] = __builtin_amdgcn_mfma_f32_16x16x32_f16(ao[v], bh[nt][ks], acc[v][nt], 0, 0, 0);
                }
        }
        __syncthreads();   // all GEMM reads of sX complete before overwrite

        if (l < 4) {
            // ---- pointwise tanh-layer epilogue (fully lane-local) ----
            const float* __restrict__ bc = bl[l];
            #pragma unroll
            for (int nt = 0; nt < 2; ++nt) {
                const int i = wn * 32 + nt * 16 + l15;
                const float bi = bc[i];
                #pragma unroll
                for (int r = 0; r < 4; ++r) {
                    const int p = wm * 16 + l4 * 4 + r;
                    const float zv = acc[0][nt][r] + bi;
                    const float hv = fast_tanh(zv);
                    const float s  = 1.0f - hv * hv;
                    const float d0 = acc[1][nt][r], d1 = acc[2][nt][r];
                    const float d2 = acc[3][nt][r], d3 = acc[4][nt][r];
                    const float ssq = ((d0 * d0 - d1 * d1) - d2 * d2) - d3 * d3;
                    const float qn  = fmaf(s, acc[5][nt][r], -2.0f * hv * s * ssq);
                    const float nv[6] = { hv, s * d0, s * d1, s * d2, s * d3, qn };
                    #pragma unroll
                    for (int v = 0; v < 6; ++v) {
                        const int idx = (v * P + p) * XPAD + i;
                        _Float16 h_, o_; split_f16(nv[v], h_, o_);
                        sXhi[idx] = h_; sXlo[idx] = o_;
                    }
                }
            }
            __syncthreads();
        } else {
            // ---- last tanh layer + linear head fused: res = W6 . q_final ----
            const float* __restrict__ bc = bl[4];
            float part[4] = { 0.f, 0.f, 0.f, 0.f };
            #pragma unroll
            for (int nt = 0; nt < 2; ++nt) {
                const int i = wn * 32 + nt * 16 + l15;
                const float bi = bc[i];
                const float w6 = W6[i];
                #pragma unroll
                for (int r = 0; r < 4; ++r) {
                    const float zv = acc[0][nt][r] + bi;
                    const float hv = fast_tanh(zv);
                    const float s  = 1.0f - hv * hv;
                    const float d0 = acc[1][nt][r], d1 = acc[2][nt][r];
                    const float d2 = acc[3][nt][r], d3 = acc[4][nt][r];
                    const float ssq = ((d0 * d0 - d1 * d1) - d2 * d2) - d3 * d3;
                    const float qf  = fmaf(s, acc[5][nt][r], -2.0f * hv * s * ssq);
                    part[r] = fmaf(w6, qf, part[r]);
                }
            }
            // reduce over the 16 lanes (l15) that hold different i for same p
            #pragma unroll
            for (int m = 1; m < 16; m <<= 1)
                #pragma unroll
                for (int r = 0; r < 4; ++r) part[r] += __shfl_xor(part[r], m, 64);
            if (l15 == 0) {
                #pragma unroll
                for (int r = 0; r < 4; ++r) sRed[wn][wm * 16 + l4 * 4 + r] = part[r];
            }
        }
    }

    __syncthreads();
    if (tid < P) {
        const float rsum = sRed[0][tid] + sRed[1][tid] + sRed[2][tid] + sRed[3][tid];
        const int o = gb + tid;
        if (o < N) out[o] = rsum;
    }
}

extern "C" void kernel_launch(void* const* d_in, const int* in_sizes, int n_in,
                              void* d_out, int out_size, void* d_ws, size_t ws_size,
                              hipStream_t stream) {
    const float* t  = (const float*)d_in[0];
    const float* x  = (const float*)d_in[1];
    const float* y  = (const float*)d_in[2];
    const float* z  = (const float*)d_in[3];
    const float* W0 = (const float*)d_in[4];
    const float* b0 = (const float*)d_in[5];
    const float* W1 = (const float*)d_in[6];
    const float* b1 = (const float*)d_in[7];
    const float* W2 = (const float*)d_in[8];
    const float* b2 = (const float*)d_in[9];
    const float* W3 = (const float*)d_in[10];
    const float* b3 = (const float*)d_in[11];
    const float* W4 = (const float*)d_in[12];
    const float* b4 = (const float*)d_in[13];
    const float* W5 = (const float*)d_in[14];
    const float* b5 = (const float*)d_in[15];
    const float* W6 = (const float*)d_in[16];
    // d_in[17] = b6: unused (drops out of all derivatives)

    const int N = in_sizes[0];
    float* out = (float*)d_out;

    const int grid = (N + P - 1) / P;
    pinn_mfma<<<grid, TPB, 0, stream>>>(
        t, x, y, z, W0, b0, W1, b1, W2, b2, W3, b3, W4, b4, W5, b5, W6, out, N);
}

// Round 4
// 181.064 us; speedup vs baseline: 8.3770x; 1.4610x over previous
//
#include <hip/hip_runtime.h>
#include <hip/hip_fp16.h>
#include <math.h>

// PhysicsResidual via 2nd-order forward-mode AD, split-fp16 MFMA, operand-swapped.
// State per point: 6 vectors of 128 (h, 4 first derivs, q = signed 2nd-deriv combo).
// Per block: 16 points. Per layer GEMM: A = W (M=128 neurons), B = X^T (N-cols =
// 6v x 16p = 96), K = 128. Split-fp16: A*B ~= Wh*Xh + Wh*Xl + Wl*Xh (fp32 acc).
// Fragment mappings (validated round 3): arg0 row = lane&15, arg1 col = lane&15,
// k = (lane>>4)*8 + e; D: col = lane&15 (=point), row = (lane>>4)*4 + reg (=neuron).
// => epilogue writes 4 consecutive neurons per lane: packed ds_write_b64.
// W1..W5 pre-split into fp16 hi/lo fragments in d_ws by a pre-kernel (fragment-
// ordered, coalesced 16B/lane loads); fallback: on-the-fly split if ws too small.

typedef _Float16 f16x8 __attribute__((ext_vector_type(8)));
typedef _Float16 f16x4 __attribute__((ext_vector_type(4)));
typedef float    f32x4 __attribute__((ext_vector_type(4)));

constexpr int TPB  = 256;
constexpr int P    = 16;    // points per block
constexpr int H    = 128;
constexpr int XPAD = 136;   // halves per padded X row (272 B)
constexpr int NV   = 6;
// pre-split W plane: 5 layers x 8 mt x 4 ks x 64 lanes x 8 halves
constexpr int WFRAG_HALVES = 5 * 8 * 4 * 64 * 8;           // 81920 halves
constexpr size_t WS_NEEDED = 2 * WFRAG_HALVES * sizeof(_Float16); // 327680 B

__device__ __forceinline__ float fast_tanh(float v) {
    float e = __expf(-2.0f * fabsf(v));
    float r = __builtin_amdgcn_rcpf(1.0f + e);
    return copysignf((1.0f - e) * r, v);
}

// ---------------- pre-split kernel: W1..W5 -> fp16 hi/lo fragments -----------
__global__ __launch_bounds__(TPB) void presplit_w(
    const float* __restrict__ W1, const float* __restrict__ W2,
    const float* __restrict__ W3, const float* __restrict__ W4,
    const float* __restrict__ W5, _Float16* __restrict__ whi,
    _Float16* __restrict__ wlo)
{
    const int gid = blockIdx.x * TPB + threadIdx.x;   // 0..10239
    const float* Ws[5] = { W1, W2, W3, W4, W5 };
    const int lane = gid & 63;
    const int rest = gid >> 6;        // 0..159
    const int ks   = rest & 3;
    const int mt   = (rest >> 2) & 7;
    const int l    = rest >> 5;       // 0..4
    const int n    = mt * 16 + (lane & 15);
    const int k0   = ks * 32 + (lane >> 4) * 8;
    const float4 u0 = *(const float4*)&Ws[l][n * H + k0];
    const float4 u1 = *(const float4*)&Ws[l][n * H + k0 + 4];
    const float vv[8] = { u0.x, u0.y, u0.z, u0.w, u1.x, u1.y, u1.z, u1.w };
    f16x8 h, o;
    #pragma unroll
    for (int e = 0; e < 8; ++e) {
        _Float16 hh = (_Float16)vv[e];
        h[e] = hh;
        o[e] = (_Float16)(vv[e] - (float)hh);
    }
    *(f16x8*)&whi[gid * 8] = h;
    *(f16x8*)&wlo[gid * 8] = o;
}

// ---------------- main kernel ------------------------------------------------
__global__ __launch_bounds__(TPB, 3) void pinn_mfma2(
    const float* __restrict__ t, const float* __restrict__ x,
    const float* __restrict__ y, const float* __restrict__ z,
    const float* __restrict__ W0, const float* __restrict__ b0,
    const float* __restrict__ W1, const float* __restrict__ b1,
    const float* __restrict__ W2, const float* __restrict__ b2,
    const float* __restrict__ W3, const float* __restrict__ b3,
    const float* __restrict__ W4, const float* __restrict__ b4,
    const float* __restrict__ W5, const float* __restrict__ b5,
    const float* __restrict__ W6,
    const _Float16* __restrict__ whi, const _Float16* __restrict__ wlo,
    int use_pre, float* __restrict__ out, int N)
{
    __shared__ _Float16 sXhi[NV * P * XPAD];   // 26112 B
    __shared__ _Float16 sXlo[NV * P * XPAD];   // 26112 B
    __shared__ float    sRed[4][P];            // 256 B -> 52480 B total

    const int tid  = threadIdx.x;
    const int lane = tid & 63;
    const int wn   = tid >> 6;     // wave 0..3: owns neuron tiles mt = wn*2 + nt
    const int l15  = lane & 15;
    const int l4   = lane >> 4;    // 0..3
    const int gb   = blockIdx.x * P;

    // ---------------- layer 0 (input dim 4, analytic tangents) -------------
    {
        const int p0 = tid >> 4;          // 0..15
        const int i0 = tid & 15;          // owns neurons i0*8 .. i0*8+7
        int gp = gb + p0; if (gp >= N) gp = N - 1;
        const float pt0 = t[gp], pt1 = x[gp], pt2 = y[gp], pt3 = z[gp];
        float nv[NV][8];
        #pragma unroll
        for (int j = 0; j < 8; ++j) {
            const int i = i0 * 8 + j;
            const float4 wv = *(const float4*)&W0[i * 4];
            const float zv = fmaf(wv.x, pt0, fmaf(wv.y, pt1, fmaf(wv.z, pt2, fmaf(wv.w, pt3, b0[i]))));
            const float hv = fast_tanh(zv);
            const float s  = 1.0f - hv * hv;
            const float ssq = ((wv.x * wv.x - wv.y * wv.y) - wv.z * wv.z) - wv.w * wv.w;
            nv[0][j] = hv;       nv[1][j] = s * wv.x; nv[2][j] = s * wv.y;
            nv[3][j] = s * wv.z; nv[4][j] = s * wv.w; nv[5][j] = -2.0f * hv * s * ssq;
        }
        #pragma unroll
        for (int v = 0; v < NV; ++v) {
            f16x8 hh, oo;
            #pragma unroll
            for (int j = 0; j < 8; ++j) {
                _Float16 h_ = (_Float16)nv[v][j];
                hh[j] = h_;
                oo[j] = (_Float16)(nv[v][j] - (float)h_);
            }
            const int off = (v * P + p0) * XPAD + i0 * 8;
            *(f16x8*)&sXhi[off] = hh;
            *(f16x8*)&sXlo[off] = oo;
        }
    }
    __syncthreads();

    const float* Wl[5] = { W1, W2, W3, W4, W5 };
    const float* bl[5] = { b1, b2, b3, b4, b5 };

    for (int l = 0; l < 5; ++l) {
        f32x4 acc[NV][2];
        #pragma unroll
        for (int v = 0; v < NV; ++v)
            #pragma unroll
            for (int nt = 0; nt < 2; ++nt) acc[v][nt] = (f32x4){0.f, 0.f, 0.f, 0.f};

        const float* __restrict__ Wc = Wl[l];

        #pragma unroll
        for (int ks = 0; ks < 4; ++ks) {
            // B frags: X hi/lo, col = point = l15, k = ks*32 + l4*8 + e
            f16x8 xh[NV], xl[NV];
            #pragma unroll
            for (int v = 0; v < NV; ++v) {
                const int base = (v * P + l15) * XPAD + ks * 32 + l4 * 8;
                xh[v] = *(const f16x8*)&sXhi[base];
                xl[v] = *(const f16x8*)&sXlo[base];
            }
            // A frags: W hi/lo, row = neuron = mt*16 + l15
            f16x8 ah[2], al[2];
            if (use_pre) {
                #pragma unroll
                for (int nt = 0; nt < 2; ++nt) {
                    const int f = ((l * 8 + (wn * 2 + nt)) * 4 + ks) * 64 + lane;
                    ah[nt] = *(const f16x8*)&whi[f * 8];
                    al[nt] = *(const f16x8*)&wlo[f * 8];
                }
            } else {
                #pragma unroll
                for (int nt = 0; nt < 2; ++nt) {
                    const int n  = (wn * 2 + nt) * 16 + l15;
                    const int k0 = ks * 32 + l4 * 8;
                    const float4 u0 = *(const float4*)&Wc[n * H + k0];
                    const float4 u1 = *(const float4*)&Wc[n * H + k0 + 4];
                    const float vv[8] = { u0.x, u0.y, u0.z, u0.w, u1.x, u1.y, u1.z, u1.w };
                    #pragma unroll
                    for (int e = 0; e < 8; ++e) {
                        _Float16 h_ = (_Float16)vv[e];
                        ah[nt][e] = h_;
                        al[nt][e] = (_Float16)(vv[e] - (float)h_);
                    }
                }
            }
            // product-major MFMA order: dependency distance 12 per acc chain
            #pragma unroll
            for (int v = 0; v < NV; ++v)
                #pragma unroll
                for (int nt = 0; nt < 2; ++nt)
                    acc[v][nt] = __builtin_amdgcn_mfma_f32_16x16x32_f16(ah[nt], xh[v], acc[v][nt], 0, 0, 0);
            #pragma unroll
            for (int v = 0; v < NV; ++v)
                #pragma unroll
                for (int nt = 0; nt < 2; ++nt)
                    acc[v][nt] = __builtin_amdgcn_mfma_f32_16x16x32_f16(ah[nt], xl[v], acc[v][nt], 0, 0, 0);
            #pragma unroll
            for (int v = 0; v < NV; ++v)
                #pragma unroll
                for (int nt = 0; nt < 2; ++nt)
                    acc[v][nt] = __builtin_amdgcn_mfma_f32_16x16x32_f16(al[nt], xh[v], acc[v][nt], 0, 0, 0);
        }
        __syncthreads();   // all GEMM reads of sX complete before overwrite

        if (l < 4) {
            // D: col = point = l15, row = neuron n = (wn*2+nt)*16 + l4*4 + r
            const float* __restrict__ bc = bl[l];
            #pragma unroll
            for (int nt = 0; nt < 2; ++nt) {
                const int n0 = (wn * 2 + nt) * 16 + l4 * 4;
                const float4 b4v = *(const float4*)&bc[n0];
                const float bb[4] = { b4v.x, b4v.y, b4v.z, b4v.w };
                float nv[NV][4];
                #pragma unroll
                for (int r = 0; r < 4; ++r) {
                    const float zv = acc[0][nt][r] + bb[r];
                    const float hv = fast_tanh(zv);
                    const float s  = 1.0f - hv * hv;
                    const float d0 = acc[1][nt][r], d1 = acc[2][nt][r];
                    const float d2 = acc[3][nt][r], d3 = acc[4][nt][r];
                    const float ssq = ((d0 * d0 - d1 * d1) - d2 * d2) - d3 * d3;
                    const float qn  = fmaf(s, acc[5][nt][r], -2.0f * hv * s * ssq);
                    nv[0][r] = hv;     nv[1][r] = s * d0; nv[2][r] = s * d1;
                    nv[3][r] = s * d2; nv[4][r] = s * d3; nv[5][r] = qn;
                }
                #pragma unroll
                for (int v = 0; v < NV; ++v) {
                    f16x4 hh, oo;
                    #pragma unroll
                    for (int r = 0; r < 4; ++r) {
                        _Float16 h_ = (_Float16)nv[v][r];
                        hh[r] = h_;
                        oo[r] = (_Float16)(nv[v][r] - (float)h_);
                    }
                    const int off = (v * P + l15) * XPAD + n0;
                    *(f16x4*)&sXhi[off] = hh;   // packed b64 write
                    *(f16x4*)&sXlo[off] = oo;
                }
            }
            __syncthreads();
        } else {
            // last tanh layer + linear head fused: res = W6 . q_final
            const float* __restrict__ bc = bl[4];
            float part = 0.0f;
            #pragma unroll
            for (int nt = 0; nt < 2; ++nt) {
                const int n0 = (wn * 2 + nt) * 16 + l4 * 4;
                const float4 b4v = *(const float4*)&bc[n0];
                const float4 w6v = *(const float4*)&W6[n0];
                const float bb[4] = { b4v.x, b4v.y, b4v.z, b4v.w };
                const float ww[4] = { w6v.x, w6v.y, w6v.z, w6v.w };
                #pragma unroll
                for (int r = 0; r < 4; ++r) {
                    const float zv = acc[0][nt][r] + bb[r];
                    const float hv = fast_tanh(zv);
                    const float s  = 1.0f - hv * hv;
                    const float d0 = acc[1][nt][r], d1 = acc[2][nt][r];
                    const float d2 = acc[3][nt][r], d3 = acc[4][nt][r];
                    const float ssq = ((d0 * d0 - d1 * d1) - d2 * d2) - d3 * d3;
                    const float qf  = fmaf(s, acc[5][nt][r], -2.0f * hv * s * ssq);
                    part = fmaf(ww[r], qf, part);
                }
            }
            // lanes {l15, l15+16, l15+32, l15+48} hold different neurons, same point
            part += __shfl_xor(part, 16, 64);
            part += __shfl_xor(part, 32, 64);
            if (lane < 16) sRed[wn][lane] = part;
        }
    }

    __syncthreads();
    if (tid < P) {
        const float rsum = sRed[0][tid] + sRed[1][tid] + sRed[2][tid] + sRed[3][tid];
        const int o = gb + tid;
        if (o < N) out[o] = rsum;
    }
}

extern "C" void kernel_launch(void* const* d_in, const int* in_sizes, int n_in,
                              void* d_out, int out_size, void* d_ws, size_t ws_size,
                              hipStream_t stream) {
    const float* t  = (const float*)d_in[0];
    const float* x  = (const float*)d_in[1];
    const float* y  = (const float*)d_in[2];
    const float* z  = (const float*)d_in[3];
    const float* W0 = (const float*)d_in[4];
    const float* b0 = (const float*)d_in[5];
    const float* W1 = (const float*)d_in[6];
    const float* b1 = (const float*)d_in[7];
    const float* W2 = (const float*)d_in[8];
    const float* b2 = (const float*)d_in[9];
    const float* W3 = (const float*)d_in[10];
    const float* b3 = (const float*)d_in[11];
    const float* W4 = (const float*)d_in[12];
    const float* b4 = (const float*)d_in[13];
    const float* W5 = (const float*)d_in[14];
    const float* b5 = (const float*)d_in[15];
    const float* W6 = (const float*)d_in[16];
    // d_in[17] = b6: unused (drops out of all derivatives)

    const int N = in_sizes[0];
    float* out = (float*)d_out;

    const int use_pre = (ws_size >= WS_NEEDED) ? 1 : 0;
    _Float16* whi = (_Float16*)d_ws;
    _Float16* wlo = whi + WFRAG_HALVES;

    if (use_pre) {
        presplit_w<<<(5 * 8 * 4 * 64) / TPB, TPB, 0, stream>>>(W1, W2, W3, W4, W5, whi, wlo);
    }
    const int grid = (N + P - 1) / P;
    pinn_mfma2<<<grid, TPB, 0, stream>>>(
        t, x, y, z, W0, b0, W1, b1, W2, b2, W3, b3, W4, b4, W5, b5, W6,
        whi, wlo, use_pre, out, N);
}